// Round 1
// baseline (18843.503 us; speedup 1.0000x reference)
//
#include <hip/hip_runtime.h>
#include <hip/hip_bf16.h>
#include <math.h>

#define EPSF 1e-7f
#define MAXNRM 0.99999f

static constexpr int Bb = 16, Ss = 128, Hh = 512, Vv = 10000, Ll = 3;
static constexpr int Nn = Bb * Ss; // 2048

__device__ inline float4 ld4(const float* p){ return *(const float4*)p; }
__device__ inline void st4(float* p, float4 v){ *(float4*)p = v; }
__device__ inline float dot4(float4 a, float4 b){ return a.x*b.x + a.y*b.y + a.z*b.z + a.w*b.w; }

// mobius_add elementwise given reductions: ((1+2uv+vv)*u + (1-uu)*v) / (1+2uv+uu*vv)
__device__ inline float mobj(float u, float v, float uv, float uu, float vv){
  float num = (1.f + 2.f*uv + vv)*u + (1.f - uu)*v;
  float den = 1.f + 2.f*uv + uu*vv;
  return num/den;
}

// ---------------- transpose W[l][j][k] -> Wt[l][k][j] ----------------
__global__ void k_transpose(const float* __restrict__ Wr, const float* __restrict__ Wz,
                            const float* __restrict__ Wh,
                            float* __restrict__ WtR, float* __restrict__ WtZ, float* __restrict__ WtH){
  int z = blockIdx.z; int l = z % 3; int m = z / 3;
  const float* src = (m==0?Wr : m==1?Wz : Wh) + (size_t)l*Hh*Hh;
  float* dst       = (m==0?WtR: m==1?WtZ: WtH) + (size_t)l*Hh*Hh;
  __shared__ float tile[32][33];
  int x = blockIdx.x*32 + threadIdx.x;
  int y0 = blockIdx.y*32;
  for(int i=threadIdx.y;i<32;i+=8) tile[i][threadIdx.x] = src[(y0+i)*Hh + x];
  __syncthreads();
  int xo = blockIdx.y*32 + threadIdx.x;
  int yo0 = blockIdx.x*32;
  for(int i=threadIdx.y;i<32;i+=8) dst[(yo0+i)*Hh + xo] = tile[threadIdx.x][i];
}

// ---------------- per-vocab constants ----------------
__global__ void k_pav(const float* __restrict__ P, const float* __restrict__ A,
                      float* __restrict__ pp, float* __restrict__ aa, float* __restrict__ pa){
  int w = threadIdx.x >> 6, lane = threadIdx.x & 63;
  int v = blockIdx.x*4 + w;
  const float4* Pr = (const float4*)(P + (size_t)v*Hh);
  const float4* Ar = (const float4*)(A + (size_t)v*Hh);
  float sp=0, sa=0, spa=0;
  #pragma unroll
  for(int i=0;i<2;i++){
    int k4 = lane*2 + i;
    float4 pv = Pr[k4], av = Ar[k4];
    sp += dot4(pv,pv); sa += dot4(av,av); spa += dot4(pv,av);
  }
  for(int o=32;o;o>>=1){ sp+=__shfl_down(sp,o); sa+=__shfl_down(sa,o); spa+=__shfl_down(spa,o); }
  if(lane==0){ pp[v]=sp; aa[v]=sqrtf(sa+EPSF); pa[v]=spa; }
}

// ---------------- embedding gather: X[t*B+b][:] = E[input[b][t]][:] ----------------
__global__ void k_embed(const int* __restrict__ inp, const float* __restrict__ E, float* __restrict__ X){
  int n = blockIdx.x; int t = n >> 4, b = n & 15;
  int tok = inp[b*Ss + t];
  int i = threadIdx.x;
  st4(X + (size_t)n*Hh + i*4, ld4(E + (size_t)tok*Hh + i*4));
}

// ---------------- row logmap0 ----------------
__global__ void k_logmap(const float* __restrict__ X, float* __restrict__ LX){
  int n = blockIdx.x; int t = threadIdx.x;
  __shared__ float sred[2];
  float4 v = ld4(X + (size_t)n*Hh + t*4);
  float ss = dot4(v,v);
  for(int o=32;o;o>>=1) ss += __shfl_down(ss,o);
  if((t&63)==0) sred[t>>6] = ss;
  __syncthreads();
  ss = sred[0]+sred[1];
  float nn = sqrtf(ss + EPSF);
  float sc = atanhf(fminf(nn, MAXNRM)) / nn;
  v.x*=sc; v.y*=sc; v.z*=sc; v.w*=sc;
  st4(LX + (size_t)n*Hh + t*4, v);
}

// ---------------- row expmap0 (in place, 3 buffers) ----------------
__global__ void k_expmap(float* __restrict__ XR, float* __restrict__ XZ, float* __restrict__ XH){
  float* Xp = blockIdx.y==0 ? XR : (blockIdx.y==1 ? XZ : XH);
  int n = blockIdx.x; int t = threadIdx.x;
  __shared__ float sred[2];
  float4 v = ld4(Xp + (size_t)n*Hh + t*4);
  float ss = dot4(v,v);
  for(int o=32;o;o>>=1) ss += __shfl_down(ss,o);
  if((t&63)==0) sred[t>>6] = ss;
  __syncthreads();
  ss = sred[0]+sred[1];
  float nn = sqrtf(ss + EPSF);
  float sc = tanhf(nn) / nn;
  v.x*=sc; v.y*=sc; v.z*=sc; v.w*=sc;
  st4(Xp + (size_t)n*Hh + t*4, v);
}

// ---------------- GEMM: C[n, 3*512] = LX[2048,512] @ {Ur|Uz|Uh}[j,k]^T ----------------
__global__ __launch_bounds__(256) void k_gemm(const float* __restrict__ A4,
    const float* __restrict__ U0, const float* __restrict__ U1, const float* __restrict__ U2,
    float* __restrict__ O0, float* __restrict__ O1, float* __restrict__ O2){
  __shared__ float As[16][65], Bs[16][65];
  int jb = blockIdx.x;            // 0..23
  int nb = blockIdx.y;            // 0..31
  int mat = jb >> 3; int j0 = (jb & 7)*64;
  const float* Bm = mat==0?U0 : (mat==1?U1:U2);
  float* Om       = mat==0?O0 : (mat==1?O1:O2);
  int tid = threadIdx.x;
  int lr = tid >> 2, lq = tid & 3;
  int tx = tid & 15, ty = tid >> 4;
  float acc[4][4] = {};
  for(int kb=0; kb<Hh; kb+=16){
    float4 av = ld4(A4 + (size_t)(nb*64+lr)*Hh + kb + lq*4);
    float4 bv = ld4(Bm + (size_t)(j0+lr)*Hh + kb + lq*4);
    As[lq*4+0][lr]=av.x; As[lq*4+1][lr]=av.y; As[lq*4+2][lr]=av.z; As[lq*4+3][lr]=av.w;
    Bs[lq*4+0][lr]=bv.x; Bs[lq*4+1][lr]=bv.y; Bs[lq*4+2][lr]=bv.z; Bs[lq*4+3][lr]=bv.w;
    __syncthreads();
    #pragma unroll
    for(int kk=0;kk<16;kk++){
      float a0=As[kk][ty*4+0], a1=As[kk][ty*4+1], a2=As[kk][ty*4+2], a3=As[kk][ty*4+3];
      float b0=Bs[kk][tx*4+0], b1=Bs[kk][tx*4+1], b2=Bs[kk][tx*4+2], b3=Bs[kk][tx*4+3];
      acc[0][0]+=a0*b0; acc[0][1]+=a0*b1; acc[0][2]+=a0*b2; acc[0][3]+=a0*b3;
      acc[1][0]+=a1*b0; acc[1][1]+=a1*b1; acc[1][2]+=a1*b2; acc[1][3]+=a1*b3;
      acc[2][0]+=a2*b0; acc[2][1]+=a2*b1; acc[2][2]+=a2*b2; acc[2][3]+=a2*b3;
      acc[3][0]+=a3*b0; acc[3][1]+=a3*b1; acc[3][2]+=a3*b2; acc[3][3]+=a3*b3;
    }
    __syncthreads();
  }
  for(int i=0;i<4;i++)
    for(int j2=0;j2<4;j2++)
      Om[(size_t)(nb*64+ty*4+i)*Hh + j0 + tx*4 + j2] = acc[i][j2];
}

// ---------------- block reduce (1024 thr, halves duplicated -> x0.5) ----------------
__device__ inline void block_reduce4(float v[4], float (*red)[4]){
  #pragma unroll
  for(int o=32;o;o>>=1){
    v[0]+=__shfl_down(v[0],o); v[1]+=__shfl_down(v[1],o);
    v[2]+=__shfl_down(v[2],o); v[3]+=__shfl_down(v[3],o);
  }
  int lane = threadIdx.x & 63, w = threadIdx.x >> 6;
  if(lane==0){ red[w][0]=v[0]; red[w][1]=v[1]; red[w][2]=v[2]; red[w][3]=v[3]; }
  __syncthreads();
  float s0=0,s1=0,s2=0,s3=0;
  #pragma unroll
  for(int i=0;i<16;i++){ s0+=red[i][0]; s1+=red[i][1]; s2+=red[i][2]; s3+=red[i][3]; }
  v[0]=s0*0.5f; v[1]=s1*0.5f; v[2]=s2*0.5f; v[3]=s3*0.5f;
  __syncthreads();
}

// ---------------- sequential GRU scan: one block per batch row ----------------
__global__ __launch_bounds__(1024) void k_scan(
    const float* __restrict__ XR, const float* __restrict__ XZ, const float* __restrict__ XH,
    const float* __restrict__ WtR, const float* __restrict__ WtZ, const float* __restrict__ WtH,
    const float* __restrict__ br, const float* __restrict__ bz, const float* __restrict__ bh,
    float* __restrict__ Xout){
  int b = blockIdx.x;
  int tid = threadIdx.x;
  int j = tid & 511;
  int hf = tid >> 9;       // 0 or 1
  __shared__ float lh[Hh], ap[Hh], mv[2*Hh];
  __shared__ float red[16][4];
  float brj = br[j], bzj = bz[j], bhj = bh[j];
  float vb[4] = { brj*brj, bzj*bzj, bhj*bhj, 0.f };
  block_reduce4(vb, red);
  float vvbr = vb[0], vvbz = vb[1], vvbh = vb[2];
  float h = 0.f;
  for(int t=0;t<Ss;t++){
    const size_t rowoff = (size_t)(t*Bb + b)*Hh;
    // lh = logmap0(h)
    float v1[4] = { h*h, 0, 0, 0 };
    block_reduce4(v1, red);
    float R1 = v1[0];
    float nh = sqrtf(R1 + EPSF);
    float lhj = (atanhf(fminf(nh,MAXNRM))/nh) * h;
    if(hf==0) lh[j] = lhj;
    __syncthreads();
    // mr (half 0) / mz (half 1)
    const float* W = hf ? WtZ : WtR;
    float acc = 0.f;
    #pragma unroll 8
    for(int k=0;k<Hh;k++) acc += W[(size_t)k*Hh + j] * lh[k];
    mv[hf*Hh + j] = acc;
    __syncthreads();
    float mr = mv[j], mz = mv[Hh + j];
    float xr = XR[rowoff + j], xz = XZ[rowoff + j], xh = XH[rowoff + j];
    float v2[4] = { mr*mr, mz*mz, xr*xr, xz*xz };
    block_reduce4(v2, red);
    float nmr = sqrtf(v2[0]+EPSF), nmz = sqrtf(v2[1]+EPSF);
    float ser = tanhf(nmr)/nmr, sez = tanhf(nmz)/nmz;
    float er = ser*mr, ez = sez*mz;
    float uu_er = ser*ser*v2[0], uu_ez = sez*sez*v2[1];
    float vvxr = v2[2], vvxz = v2[3];
    float v3[4] = { er*xr, ez*xz, xh*xh, 0.f };
    block_reduce4(v3, red);
    float t1r = mobj(er, xr, v3[0], uu_er, vvxr);
    float t1z = mobj(ez, xz, v3[1], uu_ez, vvxz);
    float vvxh = v3[2];
    float v4[4] = { t1r*brj, t1r*t1r, t1z*bzj, t1z*t1z };
    block_reduce4(v4, red);
    float t2r = mobj(t1r, brj, v4[0], v4[1], vvbr);
    float t2z = mobj(t1z, bzj, v4[2], v4[3], vvbz);
    float v5[4] = { t2r*t2r, t2z*t2z, 0, 0 };
    block_reduce4(v5, red);
    float n2r = sqrtf(v5[0]+EPSF), n2z = sqrtf(v5[1]+EPSF);
    float rg = 1.f/(1.f + expf(-(atanhf(fminf(n2r,MAXNRM))/n2r)*t2r));
    float zg = 1.f/(1.f + expf(-(atanhf(fminf(n2z,MAXNRM))/n2z)*t2z));
    if(hf==0) ap[j] = rg * lhj;
    __syncthreads();
    // mh with k-split across halves
    float pacc = 0.f;
    {
      int k0 = hf*256;
      #pragma unroll 8
      for(int k=k0;k<k0+256;k++) pacc += WtH[(size_t)k*Hh + j] * ap[k];
    }
    mv[hf*Hh + j] = pacc;
    __syncthreads();
    float mh = mv[j] + mv[Hh + j];
    float v6[4] = { mh*mh, 0, 0, 0 };
    block_reduce4(v6, red);
    float nmh = sqrtf(v6[0]+EPSF); float seh = tanhf(nmh)/nmh;
    float eh = seh*mh; float uu_eh = seh*seh*v6[0];
    float v7[4] = { eh*xh, 0, 0, 0 };
    block_reduce4(v7, red);
    float t3 = mobj(eh, xh, v7[0], uu_eh, vvxh);
    float v8[4] = { t3*bhj, t3*t3, 0, 0 };
    block_reduce4(v8, red);
    float htil = mobj(t3, bhj, v8[0], v8[1], vvbh);
    float v9[4] = { h*htil, htil*htil, 0, 0 };
    block_reduce4(v9, red);
    float delta = mobj(-h, htil, -v9[0], R1, v9[1]);
    float v10[4] = { delta*delta, 0, 0, 0 };
    block_reduce4(v10, red);
    float ndl = sqrtf(v10[0]+EPSF);
    float ld = (atanhf(fminf(ndl,MAXNRM))/ndl)*delta;
    float wv = zg * ld;
    float v11[4] = { wv*wv, 0, 0, 0 };
    block_reduce4(v11, red);
    float nw = sqrtf(v11[0]+EPSF); float sew = tanhf(nw)/nw;
    float ew = sew*wv; float vv_ew = sew*sew*v11[0];
    float v12[4] = { h*ew, 0, 0, 0 };
    block_reduce4(v12, red);
    float h2 = mobj(h, ew, v12[0], R1, vv_ew);
    float v13[4] = { h2*h2, 0, 0, 0 };
    block_reduce4(v13, red);
    float nh2 = sqrtf(v13[0]+EPSF);
    h = h2 * fminf(1.f, MAXNRM/nh2);
    if(hf==0) Xout[rowoff + j] = h;
    __syncthreads();
  }
}

// ---------------- fused MLR + online softmax partials ----------------
__global__ __launch_bounds__(256) void k_mlr(const float* __restrict__ X,
    const float* __restrict__ P, const float* __restrict__ A,
    const float* __restrict__ pp, const float* __restrict__ aa, const float* __restrict__ pa,
    const int* __restrict__ tgt, float* __restrict__ pm, float* __restrict__ tl){
  constexpr int RT = 32;
  int split = blockIdx.x;      // 0..7
  int rg = blockIdx.y;         // 0..63
  int rbase = rg*RT;
  __shared__ float Xs[RT][516];
  __shared__ float par[8][RT];
  __shared__ float ms[8][RT][2];
  __shared__ float xxs[RT];
  int tid = threadIdx.x;
  #pragma unroll
  for(int u=0;u<16;u++){
    int fi = u*256 + tid;
    int row = fi >> 7, c4 = fi & 127;
    float4 v = ld4(X + (size_t)(rbase+row)*Hh + c4*4);
    st4(&Xs[row][c4*4], v);
  }
  __syncthreads();
  { int r = tid & 31, seg = tid >> 5;
    float s = 0;
    for(int k=seg*64;k<seg*64+64;k++){ float x = Xs[r][k]; s += x*x; }
    par[seg][r] = s; }
  __syncthreads();
  if(tid < RT){ float s=0; for(int i=0;i<8;i++) s += par[i][tid]; xxs[tid]=s; }
  __syncthreads();
  int r = tid & 31, vi = tid >> 5;
  int rr = rbase + r;
  int tt = rr >> 4, bbr = rr & 15;
  int tok = tgt[bbr*Ss + tt];
  float xx = xxs[r];
  float m = -3.0e38f, sacc = 0.f;
  int v0 = split*1250, v1e = v0 + 1250;
  const float4* Xrow = (const float4*)&Xs[r][0];
  for(int vbv=v0; vbv<v1e; vbv+=8){
    int v = vbv + vi;
    if(v < v1e){
      float px=0, xa=0;
      const float4* Pr = (const float4*)(P + (size_t)v*Hh);
      const float4* Ar = (const float4*)(A + (size_t)v*Hh);
      #pragma unroll 4
      for(int k4=0;k4<128;k4++){
        float4 xv = Xrow[k4];
        float4 pv = Pr[k4]; float4 av = Ar[k4];
        px += dot4(xv,pv); xa += dot4(xv,av);
      }
      float ppv = pp[v], aav = aa[v], pav = pa[v];
      float al = 1.f - 2.f*px + xx;
      float be = 1.f - ppv;
      float gm = 1.f - 2.f*px + ppv*xx;
      float da = (-al*pav + be*xa)/gm;
      float dd = (al*al*ppv - 2.f*al*be*px + be*be*xx)/(gm*gm);
      float lam = 2.f/(1.f - ppv);
      float arg = 2.f*da/((1.f - dd)*aav + EPSF);
      float lg = lam*aav*asinhf(arg);
      if(v == tok) tl[rr] = lg;
      if(lg > m){ sacc = sacc*expf(m - lg) + 1.f; m = lg; }
      else sacc += expf(lg - m);
    }
  }
  ms[vi][r][0] = m; ms[vi][r][1] = sacc;
  __syncthreads();
  if(vi==0){
    float M = -3.0e38f;
    for(int i=0;i<8;i++) M = fmaxf(M, ms[i][r][0]);
    float Ssum = 0.f;
    for(int i=0;i<8;i++) Ssum += ms[i][r][1]*expf(ms[i][r][0]-M);
    pm[((size_t)rr*8 + split)*2 + 0] = M;
    pm[((size_t)rr*8 + split)*2 + 1] = Ssum;
  }
}

// ---------------- final merge + mean NLL ----------------
__global__ void k_final(const float* __restrict__ pm, const float* __restrict__ tl, float* __restrict__ out){
  int tid = threadIdx.x;
  __shared__ float sred[4];
  float acc = 0.f;
  for(int q=0;q<8;q++){
    int rr = q*256 + tid;
    float M = -3.0e38f;
    for(int s=0;s<8;s++) M = fmaxf(M, pm[((size_t)rr*8+s)*2]);
    float Ssum = 0.f;
    for(int s=0;s<8;s++) Ssum += pm[((size_t)rr*8+s)*2+1]*expf(pm[((size_t)rr*8+s)*2]-M);
    acc += (M + logf(Ssum)) - tl[rr];
  }
  for(int o=32;o;o>>=1) acc += __shfl_down(acc,o);
  if((tid&63)==0) sred[tid>>6] = acc;
  __syncthreads();
  if(tid==0) out[0] = (sred[0]+sred[1]+sred[2]+sred[3]) / 2048.f;
}

extern "C" void kernel_launch(void* const* d_in, const int* in_sizes, int n_in,
                              void* d_out, int out_size, void* d_ws, size_t ws_size,
                              hipStream_t stream){
  const int* inp = (const int*)d_in[0];
  const int* tgt = (const int*)d_in[1];
  const float* E  = (const float*)d_in[2];
  const float* Wr = (const float*)d_in[3];
  const float* Wz = (const float*)d_in[4];
  const float* Wh = (const float*)d_in[5];
  const float* Ur = (const float*)d_in[6];
  const float* Uz = (const float*)d_in[7];
  const float* Uh = (const float*)d_in[8];
  const float* br = (const float*)d_in[9];
  const float* bz = (const float*)d_in[10];
  const float* bh = (const float*)d_in[11];
  const float* P  = (const float*)d_in[12];
  const float* A  = (const float*)d_in[13];
  float* out = (float*)d_out;
  float* w = (float*)d_ws;
  size_t o = 0;
  auto take = [&](size_t n){ float* p = w + o; o += n; return p; };
  float* Xa  = take((size_t)Nn*Hh);
  float* Xb  = take((size_t)Nn*Hh);
  float* LX  = take((size_t)Nn*Hh);
  float* XR  = take((size_t)Nn*Hh);
  float* XZ  = take((size_t)Nn*Hh);
  float* XH  = take((size_t)Nn*Hh);
  float* WtR = take((size_t)Ll*Hh*Hh);
  float* WtZ = take((size_t)Ll*Hh*Hh);
  float* WtH = take((size_t)Ll*Hh*Hh);
  float* pp  = take(10240);
  float* aa  = take(10240);
  float* pa  = take(10240);
  float* pm  = take((size_t)Nn*8*2);
  float* tl  = take((size_t)Nn);
  if(ws_size < o*sizeof(float)) return; // workspace too small: fail loudly (output stays zero)

  hipLaunchKernelGGL(k_transpose, dim3(16,16,9), dim3(32,8), 0, stream, Wr,Wz,Wh, WtR,WtZ,WtH);
  hipLaunchKernelGGL(k_pav, dim3(2500), dim3(256), 0, stream, P,A, pp,aa,pa);
  hipLaunchKernelGGL(k_embed, dim3(Nn), dim3(128), 0, stream, inp, E, Xa);
  float* cur = Xa; float* nxt = Xb;
  for(int l=0;l<Ll;l++){
    hipLaunchKernelGGL(k_logmap, dim3(Nn), dim3(128), 0, stream, cur, LX);
    hipLaunchKernelGGL(k_gemm, dim3(24,32), dim3(256), 0, stream, LX,
                       Ur + (size_t)l*Hh*Hh, Uz + (size_t)l*Hh*Hh, Uh + (size_t)l*Hh*Hh,
                       XR, XZ, XH);
    hipLaunchKernelGGL(k_expmap, dim3(Nn,3), dim3(128), 0, stream, XR,XZ,XH);
    hipLaunchKernelGGL(k_scan, dim3(Bb), dim3(1024), 0, stream, XR,XZ,XH,
                       WtR + (size_t)l*Hh*Hh, WtZ + (size_t)l*Hh*Hh, WtH + (size_t)l*Hh*Hh,
                       br + l*Hh, bz + l*Hh, bh + l*Hh, nxt);
    float* tmp = cur; cur = nxt; nxt = tmp;
  }
  hipLaunchKernelGGL(k_mlr, dim3(8,64), dim3(256), 0, stream, cur, P, A, pp,aa,pa, tgt, pm, tl);
  hipLaunchKernelGGL(k_final, dim3(1), dim3(256), 0, stream, pm, tl, out);
}

// Round 2
// 15122.650 us; speedup vs baseline: 1.2460x; 1.2460x over previous
//
#include <hip/hip_runtime.h>
#include <hip/hip_bf16.h>
#include <math.h>

#define EPSF 1e-7f
#define MAXNRM 0.99999f

static constexpr int Bb = 16, Ss = 128, Hh = 512, Vv = 10000, Ll = 3;
static constexpr int Nn = Bb * Ss; // 2048

__device__ inline float4 ld4(const float* p){ return *(const float4*)p; }
__device__ inline void st4(float* p, float4 v){ *(float4*)p = v; }
__device__ inline float dot4(float4 a, float4 b){ return a.x*b.x + a.y*b.y + a.z*b.z + a.w*b.w; }
__device__ inline float bf_lo(unsigned u){ unsigned x = u << 16; return __builtin_bit_cast(float, x); }
__device__ inline float bf_hi(unsigned u){ unsigned x = u & 0xffff0000u; return __builtin_bit_cast(float, x); }
__device__ inline float sigm(float x){ return 1.f/(1.f + expf(-x)); }

// ---------------- transpose W[l][j][k] -> bf16 Wt[l][k][j] ----------------
__global__ void k_transw(const float* __restrict__ Wr, const float* __restrict__ Wz,
                         const float* __restrict__ Wh,
                         ushort* __restrict__ Tr, ushort* __restrict__ Tz, ushort* __restrict__ Th){
  int z = blockIdx.z; int l = z % 3; int m = z / 3;
  const float* src = (m==0?Wr : m==1?Wz : Wh) + (size_t)l*Hh*Hh;
  ushort* dst      = (m==0?Tr : m==1?Tz : Th) + (size_t)l*Hh*Hh;
  __shared__ float tile[32][33];
  int x = blockIdx.x*32 + threadIdx.x;
  int y0 = blockIdx.y*32;
  for(int i=threadIdx.y;i<32;i+=8) tile[i][threadIdx.x] = src[(size_t)(y0+i)*Hh + x];
  __syncthreads();
  int xo = blockIdx.y*32 + threadIdx.x;
  int yo0 = blockIdx.x*32;
  for(int i=threadIdx.y;i<32;i+=8){
    __hip_bfloat16 hb = __float2bfloat16(tile[threadIdx.x][i]);
    dst[(size_t)(yo0+i)*Hh + xo] = __builtin_bit_cast(unsigned short, hb);
  }
}

// ---------------- per-vocab constants ----------------
__global__ void k_pav(const float* __restrict__ P, const float* __restrict__ A,
                      float* __restrict__ pp, float* __restrict__ aa, float* __restrict__ pa){
  int w = threadIdx.x >> 6, lane = threadIdx.x & 63;
  int v = blockIdx.x*4 + w;
  const float4* Pr = (const float4*)(P + (size_t)v*Hh);
  const float4* Ar = (const float4*)(A + (size_t)v*Hh);
  float sp=0, sa=0, spa=0;
  #pragma unroll
  for(int i=0;i<2;i++){
    int k4 = lane*2 + i;
    float4 pv = Pr[k4], av = Ar[k4];
    sp += dot4(pv,pv); sa += dot4(av,av); spa += dot4(pv,av);
  }
  for(int o=32;o;o>>=1){ sp+=__shfl_down(sp,o); sa+=__shfl_down(sa,o); spa+=__shfl_down(spa,o); }
  if(lane==0){ pp[v]=sp; aa[v]=sqrtf(sa+EPSF); pa[v]=spa; }
}

// ---------------- embedding gather ----------------
__global__ void k_embed(const int* __restrict__ inp, const float* __restrict__ E, float* __restrict__ X){
  int n = blockIdx.x; int t = n >> 4, b = n & 15;
  int tok = inp[b*Ss + t];
  int i = threadIdx.x;
  st4(X + (size_t)n*Hh + i*4, ld4(E + (size_t)tok*Hh + i*4));
}

// ---------------- row logmap0 ----------------
__global__ void k_logmap(const float* __restrict__ X, float* __restrict__ LX){
  int n = blockIdx.x; int t = threadIdx.x;
  __shared__ float sred[2];
  float4 v = ld4(X + (size_t)n*Hh + t*4);
  float ss = dot4(v,v);
  for(int o=32;o;o>>=1) ss += __shfl_down(ss,o);
  if((t&63)==0) sred[t>>6] = ss;
  __syncthreads();
  ss = sred[0]+sred[1];
  float nn = sqrtf(ss + EPSF);
  float sc = atanhf(fminf(nn, MAXNRM)) / nn;
  v.x*=sc; v.y*=sc; v.z*=sc; v.w*=sc;
  st4(LX + (size_t)n*Hh + t*4, v);
}

// ---------------- row expmap0 (in place, 3 buffers) ----------------
__global__ void k_expmap(float* __restrict__ XR, float* __restrict__ XZ, float* __restrict__ XH){
  float* Xp = blockIdx.y==0 ? XR : (blockIdx.y==1 ? XZ : XH);
  int n = blockIdx.x; int t = threadIdx.x;
  __shared__ float sred[2];
  float4 v = ld4(Xp + (size_t)n*Hh + t*4);
  float ss = dot4(v,v);
  for(int o=32;o;o>>=1) ss += __shfl_down(ss,o);
  if((t&63)==0) sred[t>>6] = ss;
  __syncthreads();
  ss = sred[0]+sred[1];
  float nn = sqrtf(ss + EPSF);
  float sc = tanhf(nn) / nn;
  v.x*=sc; v.y*=sc; v.z*=sc; v.w*=sc;
  st4(Xp + (size_t)n*Hh + t*4, v);
}

// ---------------- GEMM: LX[2048,512] @ {Ur|Uz|Uh}^T ----------------
__global__ __launch_bounds__(256) void k_gemm(const float* __restrict__ A4,
    const float* __restrict__ U0, const float* __restrict__ U1, const float* __restrict__ U2,
    float* __restrict__ O0, float* __restrict__ O1, float* __restrict__ O2){
  __shared__ float As[16][65], Bs[16][65];
  int jb = blockIdx.x;
  int nb = blockIdx.y;
  int mat = jb >> 3; int j0 = (jb & 7)*64;
  const float* Bm = mat==0?U0 : (mat==1?U1:U2);
  float* Om       = mat==0?O0 : (mat==1?O1:O2);
  int tid = threadIdx.x;
  int lr = tid >> 2, lq = tid & 3;
  int tx = tid & 15, ty = tid >> 4;
  float acc[4][4] = {};
  for(int kb=0; kb<Hh; kb+=16){
    float4 av = ld4(A4 + (size_t)(nb*64+lr)*Hh + kb + lq*4);
    float4 bv = ld4(Bm + (size_t)(j0+lr)*Hh + kb + lq*4);
    As[lq*4+0][lr]=av.x; As[lq*4+1][lr]=av.y; As[lq*4+2][lr]=av.z; As[lq*4+3][lr]=av.w;
    Bs[lq*4+0][lr]=bv.x; Bs[lq*4+1][lr]=bv.y; Bs[lq*4+2][lr]=bv.z; Bs[lq*4+3][lr]=bv.w;
    __syncthreads();
    #pragma unroll
    for(int kk=0;kk<16;kk++){
      float a0=As[kk][ty*4+0], a1=As[kk][ty*4+1], a2=As[kk][ty*4+2], a3=As[kk][ty*4+3];
      float b0=Bs[kk][tx*4+0], b1=Bs[kk][tx*4+1], b2=Bs[kk][tx*4+2], b3=Bs[kk][tx*4+3];
      acc[0][0]+=a0*b0; acc[0][1]+=a0*b1; acc[0][2]+=a0*b2; acc[0][3]+=a0*b3;
      acc[1][0]+=a1*b0; acc[1][1]+=a1*b1; acc[1][2]+=a1*b2; acc[1][3]+=a1*b3;
      acc[2][0]+=a2*b0; acc[2][1]+=a2*b1; acc[2][2]+=a2*b2; acc[2][3]+=a2*b3;
      acc[3][0]+=a3*b0; acc[3][1]+=a3*b1; acc[3][2]+=a3*b2; acc[3][3]+=a3*b3;
    }
    __syncthreads();
  }
  for(int i=0;i<4;i++)
    for(int j2=0;j2<4;j2++)
      Om[(size_t)(nb*64+ty*4+i)*Hh + j0 + tx*4 + j2] = acc[i][j2];
}

// ---------------- fused dot-product block reduction ----------------
// All 1024 threads must call (contains barriers). Threads with no data pass zeros.
template<int N>
__device__ inline void block_dots(const float* v, float (*red)[16], float* sums,
                                  float* out, int lane, int w){
  float r[N];
  #pragma unroll
  for(int i=0;i<N;i++){
    float x = v[i];
    #pragma unroll
    for(int o=32;o;o>>=1) x += __shfl_down(x,o);
    r[i] = x;
  }
  if(lane==0){
    #pragma unroll
    for(int i=0;i<N;i++) red[w][i] = r[i];
  }
  __syncthreads();
  if(w==0 && lane<N){
    float s = 0;
    #pragma unroll
    for(int q=0;q<16;q++) s += red[q][lane];
    sums[lane] = s;
  }
  __syncthreads();
  #pragma unroll
  for(int i=0;i<N;i++) out[i] = sums[i];
}

// ---------------- sequential GRU scan: one block per batch row ----------------
// Gram-trick: 3 reduction passes per step; bf16 streamed weights.
__global__ __launch_bounds__(1024) void k_scan2(
    const float* __restrict__ XR, const float* __restrict__ XZ, const float* __restrict__ XH,
    const ushort* __restrict__ Tr, const ushort* __restrict__ Tz, const ushort* __restrict__ Th,
    const float* __restrict__ br, const float* __restrict__ bz, const float* __restrict__ bh,
    float* __restrict__ Xout){
  const int b = blockIdx.x;
  const int t = threadIdx.x;
  const int j = t & 511;
  const int lane = t & 63, w = t >> 6;       // 16 waves
  __shared__ float lh_s[Hh];
  __shared__ float ap_s[Hh];
  __shared__ float mz_s[Hh];
  __shared__ float part[8][Hh];              // 16KB matvec partials
  __shared__ float red[16][16];
  __shared__ float sums[16];

  // per-thread persistent state (valid for t<512; j == t)
  float h_j = 0.f, lh_j = 0.f, z_j = 0.f;
  float br_j = br[j], bz_j = bz[j], bh_j = bh[j];
  float S_h = 0.f;                            // sum(h^2), tracked analytically

  // bias Gram (once)
  float pv[3];
  if(t < 512){ pv[0]=br_j*br_j; pv[1]=bz_j*bz_j; pv[2]=bh_j*bh_j; }
  else { pv[0]=pv[1]=pv[2]=0.f; }
  float sb[3];
  block_dots<3>(pv, red, sums, sb, lane, w);
  const float bbr = sb[0], bbz = sb[1], bbh = sb[2];

  if(t < 512) lh_s[j] = 0.f;
  __syncthreads();

  for(int ts=0; ts<Ss; ts++){
    const size_t row = (size_t)(ts*Bb + b)*Hh;
    float xr_j=0.f, xz_j=0.f, xh_j=0.f;
    if(t < 512){ xr_j = XR[row+j]; xz_j = XZ[row+j]; xh_j = XH[row+j]; }

    // ---- matvec 1: mr = Tr^T-form @ lh ; mz = Tz @ lh (bf16 weights) ----
    {
      const ushort* Wm = (t>>9) ? Tz : Tr;
      int a = j & 127;            // output cols a*4 .. a*4+3
      int kq = j >> 7;            // k-quarter 0..3
      const ushort* wp = Wm + (size_t)(kq*128)*Hh + a*4;
      float4 acc = {0,0,0,0};
      #pragma unroll 4
      for(int kk=0; kk<32; kk++){
        float4 lh4 = *(const float4*)&lh_s[kq*128 + kk*4];
        #pragma unroll
        for(int i=0;i<4;i++){
          uint2 wv = *(const uint2*)(wp + (size_t)(kk*4+i)*Hh);
          float l = (&lh4.x)[i];
          acc.x += bf_lo(wv.x)*l; acc.y += bf_hi(wv.x)*l;
          acc.z += bf_lo(wv.y)*l; acc.w += bf_hi(wv.y)*l;
        }
      }
      *(float4*)&part[(t>>9)*4 + kq][a*4] = acc;
    }
    __syncthreads();
    float mr_j = 0.f, mz_j = 0.f;
    if(t < 512){
      mr_j = part[0][j]+part[1][j]+part[2][j]+part[3][j];
    } else {
      mz_s[j] = part[4][j]+part[5][j]+part[6][j]+part[7][j];
    }
    __syncthreads();
    if(t < 512) mz_j = mz_s[j];

    // ---- pass A: 14 fused dots ----
    float dv[14];
    if(t < 512){
      dv[0]=mr_j*mr_j; dv[1]=mr_j*xr_j; dv[2]=mr_j*br_j; dv[3]=xr_j*xr_j; dv[4]=xr_j*br_j;
      dv[5]=mz_j*mz_j; dv[6]=mz_j*xz_j; dv[7]=mz_j*bz_j; dv[8]=xz_j*xz_j; dv[9]=xz_j*bz_j;
      dv[10]=xh_j*xh_j; dv[11]=h_j*xh_j; dv[12]=h_j*bh_j; dv[13]=xh_j*bh_j;
    } else {
      #pragma unroll
      for(int i=0;i<14;i++) dv[i]=0.f;
    }
    float sA[14];
    block_dots<14>(dv, red, sums, sA, lane, w);
    float xhxh = sA[10], hxh = sA[11], hbh = sA[12], xhbh = sA[13];

    if(t < 512){
      // r-gate chain (t2 = c1*mr + c2*xr + c3*br)
      float nm = sqrtf(sA[0]+EPSF), se = tanhf(nm)/nm;
      float uv = se*sA[1], uu = se*se*sA[0], vv = sA[3];
      float den = 1.f + 2.f*uv + uu*vv;
      float a1 = (1.f + 2.f*uv + vv)*se/den, a2 = (1.f-uu)/den;
      float uv2 = a1*sA[2] + a2*sA[4];
      float uu2 = a1*a1*sA[0] + 2.f*a1*a2*sA[1] + a2*a2*sA[3];
      float den2 = 1.f + 2.f*uv2 + uu2*bbr;
      float b1 = (1.f + 2.f*uv2 + bbr)/den2, b2 = (1.f-uu2)/den2;
      float c1 = b1*a1, c2 = b1*a2, c3 = b2;
      float n2sq = c1*c1*sA[0] + c2*c2*sA[3] + c3*c3*bbr
                 + 2.f*(c1*c2*sA[1] + c1*c3*sA[2] + c2*c3*sA[4]);
      float nn2 = sqrtf(n2sq+EPSF);
      float s_r = atanhf(fminf(nn2,MAXNRM))/nn2;
      float r_j = sigm(s_r*(c1*mr_j + c2*xr_j + c3*br_j));
      // z-gate chain
      float nmz = sqrtf(sA[5]+EPSF), sez = tanhf(nmz)/nmz;
      float uvz = sez*sA[6], uuz = sez*sez*sA[5], vvz = sA[8];
      float denz = 1.f + 2.f*uvz + uuz*vvz;
      float az1 = (1.f + 2.f*uvz + vvz)*sez/denz, az2 = (1.f-uuz)/denz;
      float uvz2 = az1*sA[7] + az2*sA[9];
      float uuz2 = az1*az1*sA[5] + 2.f*az1*az2*sA[6] + az2*az2*sA[8];
      float denz2 = 1.f + 2.f*uvz2 + uuz2*bbz;
      float bz1 = (1.f + 2.f*uvz2 + bbz)/denz2, bz2 = (1.f-uuz2)/denz2;
      float cz1 = bz1*az1, cz2 = bz1*az2, cz3 = bz2;
      float nz2sq = cz1*cz1*sA[5] + cz2*cz2*sA[8] + cz3*cz3*bbz
                  + 2.f*(cz1*cz2*sA[6] + cz1*cz3*sA[7] + cz2*cz3*sA[9]);
      float nnz2 = sqrtf(nz2sq+EPSF);
      float s_z = atanhf(fminf(nnz2,MAXNRM))/nnz2;
      z_j = sigm(s_z*(cz1*mz_j + cz2*xz_j + cz3*bz_j));
      ap_s[j] = r_j * lh_j;
    }
    __syncthreads();

    // ---- matvec 2: mh = Th @ (r*lh) ----
    {
      int a = j & 127;
      int ko = t >> 7;           // 0..7
      const ushort* wp = Th + (size_t)(ko*64)*Hh + a*4;
      float4 acc = {0,0,0,0};
      #pragma unroll 4
      for(int kk=0; kk<16; kk++){
        float4 ap4 = *(const float4*)&ap_s[ko*64 + kk*4];
        #pragma unroll
        for(int i=0;i<4;i++){
          uint2 wv = *(const uint2*)(wp + (size_t)(kk*4+i)*Hh);
          float l = (&ap4.x)[i];
          acc.x += bf_lo(wv.x)*l; acc.y += bf_hi(wv.x)*l;
          acc.z += bf_lo(wv.y)*l; acc.w += bf_hi(wv.y)*l;
        }
      }
      *(float4*)&part[ko][a*4] = acc;
    }
    __syncthreads();
    float mh_j = 0.f;
    if(t < 512){
      #pragma unroll
      for(int q=0;q<8;q++) mh_j += part[q][j];
    }

    // ---- pass B: 4 fused dots ----
    float ev[4];
    if(t < 512){ ev[0]=mh_j*mh_j; ev[1]=mh_j*xh_j; ev[2]=mh_j*bh_j; ev[3]=h_j*mh_j; }
    else { ev[0]=ev[1]=ev[2]=ev[3]=0.f; }
    float sB[4];
    block_dots<4>(ev, red, sums, sB, lane, w);

    float wv_j = 0.f;
    if(t < 512){
      float nm3 = sqrtf(sB[0]+EPSF), se3 = tanhf(nm3)/nm3;
      float uvh = se3*sB[1], uuh = se3*se3*sB[0], vvh = xhxh;
      float denh = 1.f + 2.f*uvh + uuh*vvh;
      float a1p = (1.f + 2.f*uvh + vvh)*se3/denh, a2p = (1.f-uuh)/denh;
      float uv2h = a1p*sB[2] + a2p*xhbh;
      float uu2h = a1p*a1p*sB[0] + 2.f*a1p*a2p*sB[1] + a2p*a2p*xhxh;
      float den2h = 1.f + 2.f*uv2h + uu2h*bbh;
      float b1p = (1.f + 2.f*uv2h + bbh)/den2h, b2p = (1.f-uu2h)/den2h;
      float c1p = b1p*a1p, c2p = b1p*a2p, c3p = b2p;        // htil = c1p*mh + c2p*xh + c3p*bh
      float h_htil = c1p*sB[3] + c2p*hxh + c3p*hbh;
      float htil2 = c1p*c1p*sB[0] + c2p*c2p*xhxh + c3p*c3p*bbh
                  + 2.f*(c1p*c2p*sB[1] + c1p*c3p*sB[2] + c2p*c3p*xhbh);
      float uvD = -h_htil, uuD = S_h, vvD = htil2;
      float denD = 1.f + 2.f*uvD + uuD*vvD;
      float dd1 = (1.f + 2.f*uvD + vvD)/denD, dd2 = (1.f-uuD)/denD;
      float g0 = -dd1, g1 = dd2*c1p, g2 = dd2*c2p, g3 = dd2*c3p;
      float del2 = g0*g0*S_h + g1*g1*sB[0] + g2*g2*xhxh + g3*g3*bbh
                 + 2.f*(g0*g1*sB[3] + g0*g2*hxh + g0*g3*hbh
                      + g1*g2*sB[1] + g1*g3*sB[2] + g2*g3*xhbh);
      float ndl = sqrtf(del2+EPSF);
      float sld = atanhf(fminf(ndl,MAXNRM))/ndl;
      float delta_j = g0*h_j + g1*mh_j + g2*xh_j + g3*bh_j;
      wv_j = z_j * (sld * delta_j);
    }

    // ---- pass C: 2 fused dots ----
    float fv[2];
    if(t < 512){ fv[0]=wv_j*wv_j; fv[1]=h_j*wv_j; }
    else { fv[0]=fv[1]=0.f; }
    float sC[2];
    block_dots<2>(fv, red, sums, sC, lane, w);

    if(t < 512){
      float nw = sqrtf(sC[0]+EPSF), sew = tanhf(nw)/nw;
      float uvw = sew*sC[1], uuw = S_h, vvw = sew*sew*sC[0];
      float denw = 1.f + 2.f*uvw + uuw*vvw;
      float p1 = (1.f + 2.f*uvw + vvw)/denw, p2 = (1.f-uuw)/denw;
      float q1 = p1, q2 = p2*sew;                  // h2 = q1*h + q2*wv
      float n2h = q1*q1*S_h + 2.f*q1*q2*sC[1] + q2*q2*sC[0];  // sum(h2^2) exact
      float nrm = sqrtf(n2h+EPSF);
      float sc = fminf(1.f, MAXNRM/nrm);
      h_j = sc*(q1*h_j + q2*wv_j);
      S_h = sc*sc*n2h;
      float nh = sqrtf(S_h+EPSF);
      float slh = atanhf(fminf(nh,MAXNRM))/nh;
      lh_j = slh*h_j;
      lh_s[j] = lh_j;
      Xout[row+j] = h_j;
    }
    __syncthreads();
  }
}

// ---------------- fused MLR + online softmax partials ----------------
__global__ __launch_bounds__(256) void k_mlr(const float* __restrict__ X,
    const float* __restrict__ P, const float* __restrict__ A,
    const float* __restrict__ pp, const float* __restrict__ aa, const float* __restrict__ pa,
    const int* __restrict__ tgt, float* __restrict__ pm, float* __restrict__ tl){
  constexpr int RT = 32;
  int split = blockIdx.x;      // 0..7
  int rg = blockIdx.y;         // 0..63
  int rbase = rg*RT;
  __shared__ float Xs[RT][516];
  __shared__ float par[8][RT];
  __shared__ float ms[8][RT][2];
  __shared__ float xxs[RT];
  int tid = threadIdx.x;
  #pragma unroll
  for(int u=0;u<16;u++){
    int fi = u*256 + tid;
    int row = fi >> 7, c4 = fi & 127;
    float4 v = ld4(X + (size_t)(rbase+row)*Hh + c4*4);
    st4(&Xs[row][c4*4], v);
  }
  __syncthreads();
  { int r = tid & 31, seg = tid >> 5;
    float s = 0;
    for(int k=seg*64;k<seg*64+64;k++){ float x = Xs[r][k]; s += x*x; }
    par[seg][r] = s; }
  __syncthreads();
  if(tid < RT){ float s=0; for(int i=0;i<8;i++) s += par[i][tid]; xxs[tid]=s; }
  __syncthreads();
  int r = tid & 31, vi = tid >> 5;
  int rr = rbase + r;
  int tt = rr >> 4, bbr2 = rr & 15;
  int tok = tgt[bbr2*Ss + tt];
  float xx = xxs[r];
  float m = -3.0e38f, sacc = 0.f;
  int v0 = split*1250, v1e = v0 + 1250;
  const float4* Xrow = (const float4*)&Xs[r][0];
  for(int vbv=v0; vbv<v1e; vbv+=8){
    int v = vbv + vi;
    if(v < v1e){
      float px=0, xa=0;
      const float4* Pr = (const float4*)(P + (size_t)v*Hh);
      const float4* Ar = (const float4*)(A + (size_t)v*Hh);
      #pragma unroll 4
      for(int k4=0;k4<128;k4++){
        float4 xv = Xrow[k4];
        float4 pvv = Pr[k4]; float4 av = Ar[k4];
        px += dot4(xv,pvv); xa += dot4(xv,av);
      }
      float ppv = pp[v], aav = aa[v], pav = pa[v];
      float al = 1.f - 2.f*px + xx;
      float be = 1.f - ppv;
      float gm = 1.f - 2.f*px + ppv*xx;
      float da = (-al*pav + be*xa)/gm;
      float dd = (al*al*ppv - 2.f*al*be*px + be*be*xx)/(gm*gm);
      float lam = 2.f/(1.f - ppv);
      float arg = 2.f*da/((1.f - dd)*aav + EPSF);
      float lg = lam*aav*asinhf(arg);
      if(v == tok) tl[rr] = lg;
      if(lg > m){ sacc = sacc*expf(m - lg) + 1.f; m = lg; }
      else sacc += expf(lg - m);
    }
  }
  ms[vi][r][0] = m; ms[vi][r][1] = sacc;
  __syncthreads();
  if(vi==0){
    float M = -3.0e38f;
    for(int i=0;i<8;i++) M = fmaxf(M, ms[i][r][0]);
    float Ssum = 0.f;
    for(int i=0;i<8;i++) Ssum += ms[i][r][1]*expf(ms[i][r][0]-M);
    pm[((size_t)rr*8 + split)*2 + 0] = M;
    pm[((size_t)rr*8 + split)*2 + 1] = Ssum;
  }
}

// ---------------- final merge + mean NLL ----------------
__global__ void k_final(const float* __restrict__ pm, const float* __restrict__ tl, float* __restrict__ out){
  int tid = threadIdx.x;
  __shared__ float sred[4];
  float acc = 0.f;
  for(int q=0;q<8;q++){
    int rr = q*256 + tid;
    float M = -3.0e38f;
    for(int s=0;s<8;s++) M = fmaxf(M, pm[((size_t)rr*8+s)*2]);
    float Ssum = 0.f;
    for(int s=0;s<8;s++) Ssum += pm[((size_t)rr*8+s)*2+1]*expf(pm[((size_t)rr*8+s)*2]-M);
    acc += (M + logf(Ssum)) - tl[rr];
  }
  for(int o=32;o;o>>=1) acc += __shfl_down(acc,o);
  if((tid&63)==0) sred[tid>>6] = acc;
  __syncthreads();
  if(tid==0) out[0] = (sred[0]+sred[1]+sred[2]+sred[3]) / 2048.f;
}

extern "C" void kernel_launch(void* const* d_in, const int* in_sizes, int n_in,
                              void* d_out, int out_size, void* d_ws, size_t ws_size,
                              hipStream_t stream){
  const int* inp = (const int*)d_in[0];
  const int* tgt = (const int*)d_in[1];
  const float* E  = (const float*)d_in[2];
  const float* Wr = (const float*)d_in[3];
  const float* Wz = (const float*)d_in[4];
  const float* Wh = (const float*)d_in[5];
  const float* Ur = (const float*)d_in[6];
  const float* Uz = (const float*)d_in[7];
  const float* Uh = (const float*)d_in[8];
  const float* br = (const float*)d_in[9];
  const float* bz = (const float*)d_in[10];
  const float* bh = (const float*)d_in[11];
  const float* P  = (const float*)d_in[12];
  const float* A  = (const float*)d_in[13];
  float* out = (float*)d_out;
  float* w = (float*)d_ws;
  size_t o = 0;
  auto take = [&](size_t n){ float* p = w + o; o += n; return p; };
  float* Xa  = take((size_t)Nn*Hh);
  float* Xb  = take((size_t)Nn*Hh);
  float* LX  = take((size_t)Nn*Hh);
  float* XR  = take((size_t)Nn*Hh);
  float* XZ  = take((size_t)Nn*Hh);
  float* XH  = take((size_t)Nn*Hh);
  ushort* T2r = (ushort*)take((size_t)Ll*Hh*Hh/2);
  ushort* T2z = (ushort*)take((size_t)Ll*Hh*Hh/2);
  ushort* T2h = (ushort*)take((size_t)Ll*Hh*Hh/2);
  float* pp  = take(10240);
  float* aa  = take(10240);
  float* pa  = take(10240);
  float* pm  = take((size_t)Nn*8*2);
  float* tl  = take((size_t)Nn);
  if(ws_size < o*sizeof(float)) return;

  hipLaunchKernelGGL(k_transw, dim3(16,16,9), dim3(32,8), 0, stream, Wr,Wz,Wh, T2r,T2z,T2h);
  hipLaunchKernelGGL(k_pav, dim3(2500), dim3(256), 0, stream, P,A, pp,aa,pa);
  hipLaunchKernelGGL(k_embed, dim3(Nn), dim3(128), 0, stream, inp, E, Xa);
  float* cur = Xa; float* nxt = Xb;
  for(int l=0;l<Ll;l++){
    hipLaunchKernelGGL(k_logmap, dim3(Nn), dim3(128), 0, stream, cur, LX);
    hipLaunchKernelGGL(k_gemm, dim3(24,32), dim3(256), 0, stream, LX,
                       Ur + (size_t)l*Hh*Hh, Uz + (size_t)l*Hh*Hh, Uh + (size_t)l*Hh*Hh,
                       XR, XZ, XH);
    hipLaunchKernelGGL(k_expmap, dim3(Nn,3), dim3(128), 0, stream, XR,XZ,XH);
    hipLaunchKernelGGL(k_scan2, dim3(Bb), dim3(1024), 0, stream, XR,XZ,XH,
                       T2r + (size_t)l*Hh*Hh, T2z + (size_t)l*Hh*Hh, T2h + (size_t)l*Hh*Hh,
                       br + l*Hh, bz + l*Hh, bh + l*Hh, nxt);
    float* tmp = cur; cur = nxt; nxt = tmp;
  }
  hipLaunchKernelGGL(k_mlr, dim3(8,64), dim3(256), 0, stream, cur, P, A, pp,aa,pa, tgt, pm, tl);
  hipLaunchKernelGGL(k_final, dim3(1), dim3(256), 0, stream, pm, tl, out);
}